// Round 8
// baseline (44.613 us; speedup 1.0000x reference)
//
#include <hip/hip_runtime.h>
#include <math.h>

#define NQ   12
#define BLK  128
#define IND  768
#define HD   24
#define NOBS 28

typedef float f32x2 __attribute__((ext_vector_type(2)));

// ---- packed complex arithmetic (VOP3P, 2 FMA per instruction) ----
__device__ __forceinline__ f32x2 pk_cmul(f32x2 m, f32x2 u) {
    f32x2 r;
    asm("v_pk_mul_f32 %0, %1, %2 op_sel:[0,0] op_sel_hi:[0,1]"
        : "=v"(r) : "v"(m), "v"(u));
    asm("v_pk_fma_f32 %0, %1, %2, %0 op_sel:[1,1,0] op_sel_hi:[1,0,1] neg_lo:[0,1,0]"
        : "+v"(r) : "v"(m), "v"(u));
    return r;
}
__device__ __forceinline__ void pk_cfma(f32x2& acc, f32x2 m, f32x2 u) {
    asm("v_pk_fma_f32 %0, %1, %2, %0 op_sel:[0,0,0] op_sel_hi:[0,1,1]"
        : "+v"(acc) : "v"(m), "v"(u));
    asm("v_pk_fma_f32 %0, %1, %2, %0 op_sel:[1,1,0] op_sel_hi:[1,0,1] neg_lo:[0,1,0]"
        : "+v"(acc) : "v"(m), "v"(u));
}

// One 2x2 complex gate level on register bit M, 32-amp register state.
template<int M>
__device__ __forceinline__ void glevel(f32x2* v, const float* Mp) {
    f32x2 M0, M1, M2, M3;
    M0.x=Mp[0]; M0.y=Mp[1]; M1.x=Mp[2]; M1.y=Mp[3];
    M2.x=Mp[4]; M2.y=Mp[5]; M3.x=Mp[6]; M3.y=Mp[7];
    #pragma unroll
    for (int r = 0; r < 32; ++r)
        if (!(r & M)) {
            f32x2 u = v[r], q = v[r | M];
            f32x2 un = pk_cmul(M0, u); pk_cfma(un, M1, q);
            f32x2 qn = pk_cmul(M2, u); pk_cfma(qn, M3, q);
            v[r] = un; v[r | M] = qn;
        }
}

__global__ void __launch_bounds__(BLK) pqm_kernel(
    const float* __restrict__ x,   const float* __restrict__ W1,
    const float* __restrict__ b1,  const float* __restrict__ ln_g,
    const float* __restrict__ ln_b,const float* __restrict__ W2,
    const float* __restrict__ b2,  const float* __restrict__ qw0,
    const float* __restrict__ qw1, const float* __restrict__ qw2,
    const float* __restrict__ scales, const float* __restrict__ biases,
    float* __restrict__ out)
{
    __shared__ float stx[4096], sty[4096];   // f32 state planes (32 KB)
    __shared__ float GM[3][NQ][8];
    __shared__ float hb[HD];
    __shared__ float angc[NQ], angs[NQ];
    __shared__ float wpar[2][26];

    const int t   = threadIdx.x;
    const int w   = t >> 6;          // wave (idx bit 5, qubit 6)
    const int l   = t & 63;          // lane (idx bits 11..6, qubits 0..5)
    const int row = blockIdx.x;

    // ---- P1: stage x row into padded LDS (XA(k) = k + 4*(k>>5)) ----
    float* xs = stx;
    {
        const float4* xg = (const float4*)(x + row * IND);
        int k = 4 * t;
        *(float4*)(xs + k + 4 * (k >> 5)) = xg[t];
        if (t < 64) { int k2 = 4 * (t + 128); *(float4*)(xs + k2 + 4 * (k2 >> 5)) = xg[t + 128]; }
    }
    __syncthreads();

    // ---- P2: h = x@W1^T + b1 (8 lanes per output, 2 rounds); Rot mats ----
    {
        int l8 = t & 7;
        #pragma unroll
        for (int gg = 0; gg < 2; ++gg) {
            int g0 = (t >> 3) + 16 * gg;
            if (g0 < HD) {
                const float* wrow = W1 + g0 * IND + l8 * 96;
                const float* xp = xs + l8 * 108;
                float acc = 0.f;
                #pragma unroll
                for (int j = 0; j < 24; ++j) {
                    float4 a4 = *(const float4*)(xp + 4 * j + 4 * (j >> 3));
                    float4 w4 = *(const float4*)(wrow + 4 * j);
                    acc += a4.x * w4.x + a4.y * w4.y + a4.z * w4.z + a4.w * w4.w;
                }
                acc += __shfl_down(acc, 4, 8);
                acc += __shfl_down(acc, 2, 8);
                acc += __shfl_down(acc, 1, 8);
                if (l8 == 0) hb[g0] = acc + b1[g0];
            }
        }
    }
    if (t >= 64 && t < 100) {        // Rot matrices (wave 1)
        int u = t - 64; int li = u / NQ, q = u % NQ;
        const float* qw = (li == 0) ? qw0 : ((li == 1) ? qw1 : qw2);
        float phi = qw[q*3+0], th = qw[q*3+1], om = qw[q*3+2];
        float c = cosf(0.5f*th), s = sinf(0.5f*th);
        float sp, cp, sm, cm;
        sincosf(0.5f*(phi+om), &sp, &cp);
        sincosf(0.5f*(phi-om), &sm, &cm);
        float* R = GM[li][q];
        R[0] =  cp*c;  R[1] = -sp*c;
        R[2] = -cm*s;  R[3] = -sm*s;
        R[4] =  cm*s;  R[5] = -sm*s;
        R[6] =  cp*c;  R[7] =  sp*c;
    }
    __syncthreads();

    // ---- P3: LN + ReLU + W2 + tanh -> angles (t<12) ----
    if (t < NQ) {
        float mu = 0.f;
        #pragma unroll
        for (int j = 0; j < HD; ++j) mu += hb[j];
        mu *= (1.f / HD);
        float var = 0.f;
        #pragma unroll
        for (int j = 0; j < HD; ++j) { float d = hb[j] - mu; var += d * d; }
        var *= (1.f / HD);
        float rinv = 1.f / sqrtf(var + 1e-5f);
        float acc = b2[t];
        #pragma unroll
        for (int j = 0; j < HD; ++j) {
            float hn = (hb[j] - mu) * rinv * ln_g[j] + ln_b[j];
            acc += fmaxf(hn, 0.f) * W2[t * HD + j];
        }
        float a = tanhf(acc);
        angc[t] = cosf(0.5f * a);
        angs[t] = sinf(0.5f * a);
    }
    __syncthreads();
    // ---- P4: fuse M = Rot * RY in place ----
    if (t < 36) {
        int li = t / NQ, q = t % NQ;
        float* R = GM[li][q];
        float r0=R[0],r1=R[1],r2=R[2],r3=R[3],r4=R[4],r5=R[5],r6=R[6],r7=R[7];
        float cr = angc[q], sr = angs[q];
        R[0] =  r0*cr + r2*sr;  R[1] =  r1*cr + r3*sr;
        R[2] = -r0*sr + r2*cr;  R[3] = -r1*sr + r3*cr;
        R[4] =  r4*cr + r6*sr;  R[5] =  r5*cr + r7*sr;
        R[6] = -r4*sr + r6*cr;  R[7] = -r5*sr + r7*cr;
    }
    __syncthreads();

    // ============== circuit: idx = [l(6) | w(1) | r(5)] ==============
    // qubits: 0..5 = lane bits 5..0 ; 6 = w ; 7..11 = reg bits 4..0
    // LDS slot s(j) = (hi6<<6) | (lo6 ^ hi6)
    f32x2 v[32];

    // ---- Layer 0 via tensor-product init ----
    {
        f32x2 lf; lf.x = 1.f; lf.y = 0.f;
        #pragma unroll
        for (int k = 0; k < 6; ++k) {               // qubit k <- lane bit 5-k
            const float* F = GM[0][k];
            int bit = (l >> (5 - k)) & 1;
            f32x2 f; f.x = bit ? F[4] : F[0]; f.y = bit ? F[5] : F[1];
            lf = pk_cmul(f, lf);
        }
        { const float* F = GM[0][6];
          f32x2 f; f.x = w ? F[4] : F[0]; f.y = w ? F[5] : F[1];
          lf = pk_cmul(f, lf); }
        { const float* F = GM[0][11];
          f32x2 f0, f1; f0.x=F[0]; f0.y=F[1]; f1.x=F[4]; f1.y=F[5];
          v[1] = pk_cmul(f1, lf); v[0] = pk_cmul(f0, lf); }
        #define L0STAGE(B, Q) { const float* F = GM[0][Q]; \
            f32x2 f0, f1; f0.x=F[0]; f0.y=F[1]; f1.x=F[4]; f1.y=F[5]; \
            _Pragma("unroll") \
            for (int r = 0; r < (1 << B); ++r) { \
                v[r | (1 << B)] = pk_cmul(f1, v[r]); v[r] = pk_cmul(f0, v[r]); } }
        L0STAGE(1, 10) L0STAGE(2, 9) L0STAGE(3, 8) L0STAGE(4, 7)
        #undef L0STAGE
    }

    const int bw    = (l << 6) ^ l ^ (w << 5);  // write slot = bw ^ r
    const int pl5   = (l & 1) << 5;
    const int Bl    = l ^ (l >> 1);
    const int base0 = (Bl << 6) ^ Bl ^ pl5;     // normal-layout ring-read base
    const int base2 = (pl5 << 6) ^ pl5 ^ Bl;    // T-layout ring-read base

    #define STORE_ST() { _Pragma("unroll") \
        for (int r = 0; r < 32; ++r) { int s_ = bw ^ r; stx[s_] = v[r].x; sty[s_] = v[r].y; } }

    // ring gather (normal->normal) + qubit-6 gate of layer li
    #define RING_N_Q6(li_) { \
        __syncthreads(); STORE_ST(); __syncthreads(); \
        const float* F = GM[li_][6]; \
        f32x2 ma, mb; ma.x=F[w*4+0]; ma.y=F[w*4+1]; mb.x=F[w*4+2]; mb.y=F[w*4+3]; \
        _Pragma("unroll") \
        for (int r = 0; r < 32; ++r) { \
            const int K  = (r & 1) ? 0x30 : 0; \
            const int Br = r ^ (r >> 1); \
            const int C0 = (K << 6) ^ K ^ Br; \
            int s0_ = base0 ^ C0, s1_ = s0_ ^ 0x30; \
            f32x2 u0, u1; u0.x = stx[s0_]; u0.y = sty[s0_]; u1.x = stx[s1_]; u1.y = sty[s1_]; \
            v[r] = pk_cmul(ma, u0); pk_cfma(v[r], mb, u1); \
        } }

    // transpose (hi6<->lo6) + qubit-0 gate of layer li
    #define T_X_Q0(li_) { \
        __syncthreads(); STORE_ST(); __syncthreads(); \
        const float* F = GM[li_][0]; \
        f32x2 ma, mb; ma.x=F[w*4+0]; ma.y=F[w*4+1]; mb.x=F[w*4+2]; mb.y=F[w*4+3]; \
        _Pragma("unroll") \
        for (int r = 0; r < 32; ++r) { \
            const int C0 = (r << 6) ^ r; \
            int s0_ = l ^ C0, s1_ = s0_ ^ ((0x20 << 6) ^ 0x20); \
            f32x2 u0, u1; u0.x = stx[s0_]; u0.y = sty[s0_]; u1.x = stx[s1_]; u1.y = sty[s1_]; \
            v[r] = pk_cmul(ma, u0); pk_cfma(v[r], mb, u1); \
        } }

    // ring gather (T-layout -> normal) + qubit-6 gate of layer li
    #define RING_T_Q6(li_) { \
        __syncthreads(); STORE_ST(); __syncthreads(); \
        const float* F = GM[li_][6]; \
        f32x2 ma, mb; ma.x=F[w*4+0]; ma.y=F[w*4+1]; mb.x=F[w*4+2]; mb.y=F[w*4+3]; \
        _Pragma("unroll") \
        for (int r = 0; r < 32; ++r) { \
            const int K  = (r & 1) ? 0x30 : 0; \
            const int Br = r ^ (r >> 1); \
            const int C0 = (Br << 6) ^ Br ^ K; \
            int s0_ = base2 ^ C0, s1_ = s0_ ^ ((0x30 << 6) ^ 0x30); \
            f32x2 u0, u1; u0.x = stx[s0_]; u0.y = sty[s0_]; u1.x = stx[s1_]; u1.y = sty[s1_]; \
            v[r] = pk_cmul(ma, u0); pk_cfma(v[r], mb, u1); \
        } }

    // ring gather (T-layout -> normal), no gate (final ring)
    #define RING_T_PLAIN() { \
        __syncthreads(); STORE_ST(); __syncthreads(); \
        const int wS = w ? ((0x30 << 6) ^ 0x30) : 0; \
        _Pragma("unroll") \
        for (int r = 0; r < 32; ++r) { \
            const int K  = (r & 1) ? 0x30 : 0; \
            const int Br = r ^ (r >> 1); \
            const int C0 = (Br << 6) ^ Br ^ K; \
            int s_ = base2 ^ wS ^ C0; \
            v[r].x = stx[s_]; v[r].y = sty[s_]; \
        } }

    // Layer 1
    RING_N_Q6(1);
    glevel<16>(v, GM[1][7]); glevel<8>(v, GM[1][8]); glevel<4>(v, GM[1][9]);
    glevel<2>(v, GM[1][10]); glevel<1>(v, GM[1][11]);
    T_X_Q0(1);
    glevel<16>(v, GM[1][1]); glevel<8>(v, GM[1][2]); glevel<4>(v, GM[1][3]);
    glevel<2>(v, GM[1][4]); glevel<1>(v, GM[1][5]);
    // Layer 2
    RING_T_Q6(2);
    glevel<16>(v, GM[2][7]); glevel<8>(v, GM[2][8]); glevel<4>(v, GM[2][9]);
    glevel<2>(v, GM[2][10]); glevel<1>(v, GM[2][11]);
    T_X_Q0(2);
    glevel<16>(v, GM[2][1]); glevel<8>(v, GM[2][2]); glevel<4>(v, GM[2][3]);
    glevel<2>(v, GM[2][4]); glevel<1>(v, GM[2][5]);
    // Final ring -> true final state, normal layout
    RING_T_PLAIN();

    // ================= measurement (true masks) =================
    // eX_q: single-bit masks, idx bit 11-q -> lane masks 0x20,0x10,8,4,2
    float ex[5];
    #pragma unroll
    for (int i = 0; i < 5; ++i) {
        const int Lm = 0x20 >> i;
        float acc = 0.f;
        #pragma unroll
        for (int r = 0; r < 32; ++r) {
            float px = __shfl_xor(v[r].x, Lm, 64);
            float py = __shfl_xor(v[r].y, Lm, 64);
            acc += v[r].x * px + v[r].y * py;
        }
        ex[i] = acc;
    }

    // probabilities into v[].x, 5-level register WHT
    #pragma unroll
    for (int r = 0; r < 32; ++r) v[r].x = v[r].x * v[r].x + v[r].y * v[r].y;
    #pragma unroll
    for (int lev = 0; lev < 5; ++lev) {
        const int m = 1 << lev;
        #pragma unroll
        for (int r = 0; r < 32; ++r)
            if (!(r & m)) { float A = v[r].x, B = v[r | m].x; v[r].x = A + B; v[r | m].x = A - B; }
    }

    // laneWHT of prW[0]: lane m holds sum with sign (-1)^popc(m & l)
    float ch = v[0].x;
    #pragma unroll
    for (int lev = 0; lev < 6; ++lev) {
        float o = __shfl_xor(ch, 1 << lev, 64);
        ch = (l & (1 << lev)) ? (o - ch) : (ch + o);
    }

    auto wsum = [&](float s) {
        #pragma unroll
        for (int d = 1; d < 64; d <<= 1) s += __shfl_xor(s, d, 64);
        return s;
    };
    float q7s   = wsum(v[16].x);
    float q8s   = wsum(v[8].x);
    float q9s   = wsum(v[4].x);
    float q10s  = wsum(v[2].x);
    float q11s  = wsum(v[1].x);
    float zz78  = wsum(v[0x18].x);
    float zz89  = wsum(v[0xC].x);
    float zz910 = wsum(v[6].x);
    float zz1011= wsum(v[3].x);
    float e0 = wsum(ex[0]), e1 = wsum(ex[1]), e2 = wsum(ex[2]);
    float e3 = wsum(ex[3]), e4 = wsum(ex[4]);

    if      (l == 32) wpar[w][0]  = ch;
    else if (l == 16) wpar[w][1]  = ch;
    else if (l == 8)  wpar[w][2]  = ch;
    else if (l == 4)  wpar[w][3]  = ch;
    else if (l == 2)  wpar[w][4]  = ch;
    else if (l == 1)  wpar[w][5]  = ch;
    else if (l == 48) wpar[w][7]  = ch;
    else if (l == 24) wpar[w][8]  = ch;
    else if (l == 12) wpar[w][9]  = ch;
    else if (l == 6)  wpar[w][10] = ch;
    else if (l == 3)  wpar[w][11] = ch;
    else if (l == 0) {
        wpar[w][6]  = ch;
        wpar[w][12] = q7s;  wpar[w][13] = q8s;  wpar[w][14] = q9s;
        wpar[w][15] = q10s; wpar[w][16] = q11s;
        wpar[w][17] = zz78; wpar[w][18] = zz89; wpar[w][19] = zz910; wpar[w][20] = zz1011;
        wpar[w][21] = e0; wpar[w][22] = e1; wpar[w][23] = e2; wpar[w][24] = e3; wpar[w][25] = e4;
    }
    __syncthreads();

    if (t < NOBS) {
        const int oslot[NOBS] = {0,1,2,3,4,5,6,12,13,14,15,16,
                                 7,8,9,10,11,5,12,17,18,19,20,
                                 21,22,23,24,25};
        const int osgn[NOBS]  = {0,0,0,0,0,0,1,0,0,0,0,0,
                                 0,0,0,0,0,1,1,0,0,0,0,
                                 0,0,0,0,0};
        float a = wpar[0][oslot[t]], b = wpar[1][oslot[t]];
        float s = osgn[t] ? (a - b) : (a + b);
        out[row * NOBS + t] = s * scales[t] + biases[t];
    }
}

extern "C" void kernel_launch(void* const* d_in, const int* in_sizes, int n_in,
                              void* d_out, int out_size, void* d_ws, size_t ws_size,
                              hipStream_t stream) {
    const int Bn = in_sizes[0] / IND;   // 1024
    pqm_kernel<<<dim3(Bn), dim3(BLK), 0, stream>>>(
        (const float*)d_in[0], (const float*)d_in[1], (const float*)d_in[2],
        (const float*)d_in[3], (const float*)d_in[4], (const float*)d_in[5],
        (const float*)d_in[6], (const float*)d_in[7], (const float*)d_in[8],
        (const float*)d_in[9], (const float*)d_in[10], (const float*)d_in[11],
        (float*)d_out);
}

// Round 9
// 33.266 us; speedup vs baseline: 1.3411x; 1.3411x over previous
//
#include <hip/hip_runtime.h>
#include <math.h>

#define NQ   12
#define BLK  64
#define IND  768
#define HD   24
#define NOBS 28
#define CSTR 20   // LDS column stride in dwords (80B: 16B-aligned, 2-way banks)

typedef float    f32x2 __attribute__((ext_vector_type(2)));
typedef float    f32x4 __attribute__((ext_vector_type(4)));
typedef __fp16   f16x2 __attribute__((ext_vector_type(2)));
typedef _Float16 h8    __attribute__((ext_vector_type(8)));

__device__ __forceinline__ unsigned pkrtz(float x, float y) {
    f16x2 h = __builtin_amdgcn_cvt_pkrtz(x, y);
    unsigned u; __builtin_memcpy(&u, &h, 4); return u;
}
__device__ __forceinline__ f32x2 unpack2(unsigned u) {
    f16x2 h; __builtin_memcpy(&h, &u, 4);
    f32x2 v; v.x = (float)h.x; v.y = (float)h.y; return v;
}
__device__ __forceinline__ f32x2 pk_cmul(f32x2 m, f32x2 u) {
    f32x2 r;
    asm("v_pk_mul_f32 %0, %1, %2 op_sel:[0,0] op_sel_hi:[0,1]"
        : "=v"(r) : "v"(m), "v"(u));
    asm("v_pk_fma_f32 %0, %1, %2, %0 op_sel:[1,1,0] op_sel_hi:[1,0,1] neg_lo:[0,1,0]"
        : "+v"(r) : "v"(m), "v"(u));
    return r;
}
__device__ __forceinline__ void pk_fma_plain(f32x2& acc, f32x2 a, f32x2 b) {
    asm("v_pk_fma_f32 %0, %1, %2, %0" : "+v"(acc) : "v"(a), "v"(b));
}
__device__ __forceinline__ h8 as_h8(uint4 u) { h8 r; __builtin_memcpy(&r, &u, 16); return r; }

// prefix-XOR = T^{-1} for T(j)=j^(j>>1); ring-inverse = pfx ^ (parity?0x800:0)
__device__ __forceinline__ int pfx12(int y) { y ^= y >> 1; y ^= y >> 2; y ^= y >> 4; y ^= y >> 8; return y; }
__device__ __forceinline__ int pfx8 (int y) { y ^= y >> 1; y ^= y >> 2; y ^= y >> 4; return y; }

// One 4-qubit group GEMM stage: C(32x256) = A(32x32) * X(32x256) via 2x16 MFMAs.
// Group G = idx bits [4G,4G+4); LI = layer. WM: write mode
//   0: G0 -> G1 layout   1: G1 -> G2 layout
//   2: G2 -> G0 layout with ring fold   3: G2 -> G2 layout with ring fold
template<int LI, int G, int WM>
__device__ __forceinline__ void gstage(unsigned* st, const float GM[3][NQ][8], int l) {
    const int a  = l & 15;          // A row / B,D column (within tile)
    const int mb = (l >> 4) * 4;    // k-block (A,B) and D row-block

    // ---- A fragments: U[a,b] = prod_p gate(q=11-4G-p)[a_p,b_p] ----
    unsigned A0u[4], A1u[4];
    #pragma unroll
    for (int bi = 0; bi < 4; ++bi) {
        const int bq = mb + bi;
        f32x2 u;
        {
            const float* F = GM[LI][11 - 4*G];
            const int off = (a & 1) * 4 + (bq & 1) * 2;
            u.x = F[off]; u.y = F[off + 1];
        }
        #pragma unroll
        for (int p = 1; p < 4; ++p) {
            const float* F = GM[LI][11 - 4*G - p];
            const int off = ((a >> p) & 1) * 4 + ((bq >> p) & 1) * 2;
            f32x2 e; e.x = F[off]; e.y = F[off + 1];
            u = pk_cmul(e, u);
        }
        A0u[bi] = pkrtz(u.x, -u.y);   // Cr row: (Ur, -Ui) per k-pair
        A1u[bi] = pkrtz(u.y,  u.x);   // Ci row: (Ui,  Ur)
    }

    __syncthreads();
    // ---- preload ALL B fragments (in-place safety: reads before any write) ----
    uint4 Bf[16];
    #pragma unroll
    for (int t = 0; t < 16; ++t)
        Bf[t] = *(const uint4*)(st + (16 * t + a) * CSTR + mb);
    asm volatile("" ::: "memory");   // keep stores below from moving above reads

    uint4 A04; A04.x = A0u[0]; A04.y = A0u[1]; A04.z = A0u[2]; A04.w = A0u[3];
    uint4 A14; A14.x = A1u[0]; A14.y = A1u[1]; A14.z = A1u[2]; A14.w = A1u[3];
    const h8 A0 = as_h8(A04), A1 = as_h8(A14);

    int TL = 0;
    if (WM >= 2) TL = pfx12(mb << 8);
    const int CTJ[4] = {0, 0x1FF, 0x3FF, 0x200};   // pfx12(ji<<8)

    #pragma unroll
    for (int t = 0; t < 16; ++t) {
        f32x4 c0 = {0.f, 0.f, 0.f, 0.f}, c1 = {0.f, 0.f, 0.f, 0.f};
        const h8 Bh = as_h8(Bf[t]);
        c0 = __builtin_amdgcn_mfma_f32_16x16x32_f16(A0, Bh, c0, 0, 0, 0);
        c1 = __builtin_amdgcn_mfma_f32_16x16x32_f16(A1, Bh, c1, 0, 0, 0);
        const int n  = 16 * t + a;
        const int TN = (WM >= 2) ? (pfx8(n) ^ TL) : 0;
        #pragma unroll
        for (int j = 0; j < 4; ++j) {
            const int m = mb + j;
            int addr;
            if (WM == 0)      addr = (m | (n & 0xF0)) * CSTR + (n & 15);
            else if (WM == 1) addr = ((n & 15) | (m << 4)) * CSTR + (n >> 4);
            else {
                const int tt = TN ^ CTJ[j];
                const int jp = tt ^ ((tt & 1) << 11);
                addr = (WM == 2) ? ((jp >> 4) * CSTR + (jp & 15))
                                 : ((jp & 255) * CSTR + (jp >> 8));
            }
            st[addr] = pkrtz(c0[j], c1[j]);
        }
    }
}

__global__ void __launch_bounds__(BLK) pqm_kernel(
    const float* __restrict__ x,   const float* __restrict__ W1,
    const float* __restrict__ b1,  const float* __restrict__ ln_g,
    const float* __restrict__ ln_b,const float* __restrict__ W2,
    const float* __restrict__ b2,  const float* __restrict__ qw0,
    const float* __restrict__ qw1, const float* __restrict__ qw2,
    const float* __restrict__ scales, const float* __restrict__ biases,
    float* __restrict__ out)
{
    __shared__ unsigned st[256 * CSTR];   // f16 state, (re,im)-packed, 20KB
    __shared__ float GM[3][NQ][8];
    __shared__ float hb[HD];
    __shared__ float ang[2 * NQ];
    __shared__ float obsl[NOBS];

    const int l   = threadIdx.x;
    const int row = blockIdx.x;

    // ---- P1: stage x row into LDS ----
    float* xs = (float*)st;
    {
        const float4* xg = (const float4*)(x + row * IND);
        #pragma unroll
        for (int k = 0; k < 3; ++k)
            ((float4*)xs)[l + 64 * k] = xg[l + 64 * k];
    }
    __syncthreads();

    // ---- P2: h = x@W1^T + b1 (3 rounds of 8 outputs x 8 lanes) ----
    {
        int l8 = l & 7;
        #pragma unroll
        for (int rd = 0; rd < 3; ++rd) {
            int g = rd * 8 + (l >> 3);
            const float* wp = W1 + g * IND + l8 * 96;
            const float* xp = xs + l8 * 96;
            float acc = 0.f;
            #pragma unroll
            for (int j = 0; j < 24; ++j) {
                float4 w4 = *(const float4*)(wp + 4 * j);
                float4 a4 = *(const float4*)(xp + 4 * j);
                acc += a4.x * w4.x + a4.y * w4.y + a4.z * w4.z + a4.w * w4.w;
            }
            acc += __shfl_down(acc, 4, 8);
            acc += __shfl_down(acc, 2, 8);
            acc += __shfl_down(acc, 1, 8);
            if (l8 == 0) hb[g] = acc + b1[g];
        }
    }
    __syncthreads();

    // ---- P3: LN+ReLU+W2+tanh -> angles (lanes 0-11); Rot mats (12-47) ----
    if (l < NQ) {
        float mu = 0.f;
        #pragma unroll
        for (int j = 0; j < HD; ++j) mu += hb[j];
        mu *= (1.f / HD);
        float var = 0.f;
        #pragma unroll
        for (int j = 0; j < HD; ++j) { float d = hb[j] - mu; var += d * d; }
        var *= (1.f / HD);
        float rinv = 1.f / sqrtf(var + 1e-5f);
        float acc = b2[l];
        #pragma unroll
        for (int j = 0; j < HD; ++j) {
            float hn = (hb[j] - mu) * rinv * ln_g[j] + ln_b[j];
            acc += fmaxf(hn, 0.f) * W2[l * HD + j];
        }
        float a = tanhf(acc);
        ang[l]      = cosf(0.5f * a);
        ang[NQ + l] = sinf(0.5f * a);
    } else if (l < 48) {
        int li = (l - 12) / NQ, q = (l - 12) % NQ;
        const float* qw = (li == 0) ? qw0 : ((li == 1) ? qw1 : qw2);
        float phi = qw[q*3+0], th = qw[q*3+1], om = qw[q*3+2];
        float c = cosf(0.5f*th), s = sinf(0.5f*th);
        float sp, cp, sm, cm;
        sincosf(0.5f*(phi+om), &sp, &cp);
        sincosf(0.5f*(phi-om), &sm, &cm);
        float* R = GM[li][q];
        R[0] =  cp*c;  R[1] = -sp*c;
        R[2] = -cm*s;  R[3] = -sm*s;
        R[4] =  cm*s;  R[5] = -sm*s;
        R[6] =  cp*c;  R[7] =  sp*c;
    }
    __syncthreads();
    // ---- P4: fuse M = Rot * RY in place ----
    if (l < 36) {
        int li = l / NQ, q = l % NQ;
        float* R = GM[li][q];
        float r0=R[0],r1=R[1],r2=R[2],r3=R[3],r4=R[4],r5=R[5],r6=R[6],r7=R[7];
        float cr = ang[q], sr = ang[NQ + q];
        R[0] =  r0*cr + r2*sr;  R[1] =  r1*cr + r3*sr;
        R[2] = -r0*sr + r2*cr;  R[3] = -r1*sr + r3*cr;
        R[4] =  r4*cr + r6*sr;  R[5] =  r5*cr + r7*sr;
        R[6] = -r4*sr + r6*cr;  R[7] = -r5*sr + r7*cr;
    }
    __syncthreads();

    // ---- Layer 0 on |0..0>: tensor product; write with ring fold -> G0 layout ----
    // j = (l<<6) | r : lane bit u = j bit 6+u (qubit 5-u); reg bit b = j bit b (qubit 11-b)
    {
        f32x2 v[64];
        f32x2 lf; lf.x = 1.f; lf.y = 0.f;
        #pragma unroll
        for (int u = 0; u < 6; ++u) {
            const float* F = GM[0][5 - u];
            const int bit = (l >> u) & 1;
            f32x2 e; e.x = F[bit * 4]; e.y = F[bit * 4 + 1];
            lf = pk_cmul(e, lf);
        }
        {
            const float* F = GM[0][11];
            f32x2 e0; e0.x = F[0]; e0.y = F[1];
            f32x2 e1; e1.x = F[4]; e1.y = F[5];
            v[0] = pk_cmul(e0, lf); v[1] = pk_cmul(e1, lf);
        }
        #pragma unroll
        for (int b = 1; b < 6; ++b) {
            const float* F = GM[0][11 - b];
            f32x2 e0; e0.x = F[0]; e0.y = F[1];
            f32x2 e1; e1.x = F[4]; e1.y = F[5];
            #pragma unroll
            for (int r = 0; r < (1 << b); ++r) {
                v[r | (1 << b)] = pk_cmul(e1, v[r]);
                v[r]            = pk_cmul(e0, v[r]);
            }
        }
        const int TL6 = pfx12(l << 6);
        #pragma unroll
        for (int r = 0; r < 64; ++r) {
            int tr = r ^ (r >> 1); tr ^= tr >> 2; tr ^= tr >> 4;
            const int tt = TL6 ^ tr;
            const int jp = tt ^ ((tt & 1) << 11);
            st[(jp >> 4) * CSTR + (jp & 15)] = pkrtz(v[r].x, v[r].y);
        }
    }

    // ---- Layers 1 & 2: 6 group-GEMMs, rings folded into layer-final writes ----
    gstage<1, 0, 0>(st, GM, l);
    gstage<1, 1, 1>(st, GM, l);
    gstage<1, 2, 2>(st, GM, l);   // + ring -> G0 layout
    gstage<2, 0, 0>(st, GM, l);
    gstage<2, 1, 1>(st, GM, l);
    gstage<2, 2, 3>(st, GM, l);   // + final ring -> G2/measurement layout
    __syncthreads();

    // ---- Measurement: j = (r<<6)|l ; reg bits = qubits 5..0, lane bits = qubits 11..6 ----
    {
        f32x2 v[64];
        #pragma unroll
        for (int r = 0; r < 64; ++r) {
            const int n = ((r & 3) << 6) | l;
            v[r] = unpack2(st[n * CSTR + (r >> 2)]);
        }
        // eX q0..4: X on j-bit 11-q = reg bit 5-q; sum over all r double-counts = the x2
        float ex[5];
        #pragma unroll
        for (int q = 0; q < 5; ++q) {
            f32x2 acc; acc.x = 0.f; acc.y = 0.f;
            #pragma unroll
            for (int r = 0; r < 64; ++r) pk_fma_plain(acc, v[r], v[r ^ (0x20 >> q)]);
            ex[q] = acc.x + acc.y;
        }
        // probabilities + 6-level register WHT
        #pragma unroll
        for (int r = 0; r < 64; ++r) v[r].x = v[r].x * v[r].x + v[r].y * v[r].y;
        #pragma unroll
        for (int lev = 0; lev < 6; ++lev) {
            const int m = 1 << lev;
            #pragma unroll
            for (int r = 0; r < 64; ++r)
                if (!(r & m)) {
                    float A = v[r].x, B = v[r | m].x;
                    v[r].x = A + B; v[r | m].x = A - B;
                }
        }
        auto wsum = [&](float s) {
            #pragma unroll
            for (int d = 1; d < 64; d <<= 1) s += __shfl_xor(s, d, 64);
            return s;
        };
        // lane-WHT of W[0] for lane-side Z observables
        float ch = v[0].x;
        #pragma unroll
        for (int lev = 0; lev < 6; ++lev) {
            float o = __shfl_xor(ch, 1 << lev, 64);
            ch = (l & (1 << lev)) ? (o - ch) : (ch + o);
        }
        float z0 = wsum(v[0x20].x), z1 = wsum(v[0x10].x), z2 = wsum(v[8].x);
        float z3 = wsum(v[4].x),    z4 = wsum(v[2].x),    z5 = wsum(v[1].x);
        float zz0 = wsum(v[0x30].x), zz1 = wsum(v[0x18].x), zz2 = wsum(v[0xC].x);
        float zz3 = wsum(v[6].x),    zz4 = wsum(v[3].x);
        float zz5 = wsum((l & 0x20) ? -v[1].x : v[1].x);
        float e0 = wsum(ex[0]), e1 = wsum(ex[1]), e2 = wsum(ex[2]);
        float e3 = wsum(ex[3]), e4 = wsum(ex[4]);

        if (l == 0) {
            obsl[0] = z0; obsl[1] = z1; obsl[2] = z2;
            obsl[3] = z3; obsl[4] = z4; obsl[5] = z5;
            obsl[12] = zz0; obsl[13] = zz1; obsl[14] = zz2;
            obsl[15] = zz3; obsl[16] = zz4; obsl[17] = zz5;
            obsl[23] = e0; obsl[24] = e1; obsl[25] = e2;
            obsl[26] = e3; obsl[27] = e4;
        }
        if (l == 32) obsl[6]  = ch;
        if (l == 16) obsl[7]  = ch;
        if (l == 8)  obsl[8]  = ch;
        if (l == 4)  obsl[9]  = ch;
        if (l == 2)  obsl[10] = ch;
        if (l == 1)  obsl[11] = ch;
        if (l == 48) obsl[18] = ch;
        if (l == 24) obsl[19] = ch;
        if (l == 12) obsl[20] = ch;
        if (l == 6)  obsl[21] = ch;
        if (l == 3)  obsl[22] = ch;
    }
    __syncthreads();

    if (l < NOBS)
        out[row * NOBS + l] = obsl[l] * scales[l] + biases[l];
}

extern "C" void kernel_launch(void* const* d_in, const int* in_sizes, int n_in,
                              void* d_out, int out_size, void* d_ws, size_t ws_size,
                              hipStream_t stream) {
    const int Bn = in_sizes[0] / IND;   // 1024
    pqm_kernel<<<dim3(Bn), dim3(BLK), 0, stream>>>(
        (const float*)d_in[0], (const float*)d_in[1], (const float*)d_in[2],
        (const float*)d_in[3], (const float*)d_in[4], (const float*)d_in[5],
        (const float*)d_in[6], (const float*)d_in[7], (const float*)d_in[8],
        (const float*)d_in[9], (const float*)d_in[10], (const float*)d_in[11],
        (float*)d_out);
}

// Round 10
// 29.058 us; speedup vs baseline: 1.5353x; 1.1448x over previous
//
#include <hip/hip_runtime.h>
#include <math.h>

#define NQ   12
#define BLK  256
#define IND  768
#define HD   24
#define NOBS 28
#define CSTR 20   // LDS column stride in dwords (80B)

typedef float    f32x2 __attribute__((ext_vector_type(2)));
typedef float    f32x4 __attribute__((ext_vector_type(4)));
typedef __fp16   f16x2 __attribute__((ext_vector_type(2)));
typedef _Float16 h8    __attribute__((ext_vector_type(8)));

__device__ __forceinline__ unsigned pkrtz(float x, float y) {
    f16x2 h = __builtin_amdgcn_cvt_pkrtz(x, y);
    unsigned u; __builtin_memcpy(&u, &h, 4); return u;
}
__device__ __forceinline__ f32x2 unpack2(unsigned u) {
    f16x2 h; __builtin_memcpy(&h, &u, 4);
    f32x2 v; v.x = (float)h.x; v.y = (float)h.y; return v;
}
__device__ __forceinline__ f32x2 pk_cmul(f32x2 m, f32x2 u) {
    f32x2 r;
    asm("v_pk_mul_f32 %0, %1, %2 op_sel:[0,0] op_sel_hi:[0,1]"
        : "=v"(r) : "v"(m), "v"(u));
    asm("v_pk_fma_f32 %0, %1, %2, %0 op_sel:[1,1,0] op_sel_hi:[1,0,1] neg_lo:[0,1,0]"
        : "+v"(r) : "v"(m), "v"(u));
    return r;
}
__device__ __forceinline__ void pk_fma_plain(f32x2& acc, f32x2 a, f32x2 b) {
    asm("v_pk_fma_f32 %0, %1, %2, %0" : "+v"(acc) : "v"(a), "v"(b));
}
__device__ __forceinline__ h8 as_h8(uint4 u) { h8 r; __builtin_memcpy(&r, &u, 16); return r; }

__device__ __forceinline__ int pfx12(int y) { y ^= y >> 1; y ^= y >> 2; y ^= y >> 4; y ^= y >> 8; return y; }
__device__ __forceinline__ int pfx8 (int y) { y ^= y >> 1; y ^= y >> 2; y ^= y >> 4; return y; }

// 4-qubit group GEMM stage, split over 4 waves (4 N-tiles each).
// WM: 0: G0->G1  1: G1->G2  2: G2->G0 +ring  3: G2->meas +ring
template<int LI, int G, int WM>
__device__ __forceinline__ void gstage(unsigned* st, const float GM[3][NQ][8],
                                       int l, int w) {
    const int a  = l & 15;
    const int mb = (l >> 4) * 4;

    unsigned A0u[4], A1u[4];
    #pragma unroll
    for (int bi = 0; bi < 4; ++bi) {
        const int bq = mb + bi;
        f32x2 u;
        {
            const float* F = GM[LI][11 - 4*G];
            const int off = (a & 1) * 4 + (bq & 1) * 2;
            u.x = F[off]; u.y = F[off + 1];
        }
        #pragma unroll
        for (int p = 1; p < 4; ++p) {
            const float* F = GM[LI][11 - 4*G - p];
            const int off = ((a >> p) & 1) * 4 + ((bq >> p) & 1) * 2;
            f32x2 e; e.x = F[off]; e.y = F[off + 1];
            u = pk_cmul(e, u);
        }
        A0u[bi] = pkrtz(u.x, -u.y);
        A1u[bi] = pkrtz(u.y,  u.x);
    }

    __syncthreads();                 // prior stage writes visible
    uint4 Bf[4];
    #pragma unroll
    for (int tt = 0; tt < 4; ++tt)
        Bf[tt] = *(const uint4*)(st + (16 * (4*w + tt) + a) * CSTR + mb);
    __syncthreads();                 // all reads done before any write

    uint4 A04; A04.x = A0u[0]; A04.y = A0u[1]; A04.z = A0u[2]; A04.w = A0u[3];
    uint4 A14; A14.x = A1u[0]; A14.y = A1u[1]; A14.z = A1u[2]; A14.w = A1u[3];
    const h8 A0 = as_h8(A04), A1 = as_h8(A14);

    int TL = 0;
    if (WM >= 2) TL = pfx12(mb << 8);
    const int CTJ[4] = {0, 0x1FF, 0x3FF, 0x200};

    #pragma unroll
    for (int tt = 0; tt < 4; ++tt) {
        f32x4 c0 = {0.f, 0.f, 0.f, 0.f}, c1 = {0.f, 0.f, 0.f, 0.f};
        const h8 Bh = as_h8(Bf[tt]);
        c0 = __builtin_amdgcn_mfma_f32_16x16x32_f16(A0, Bh, c0, 0, 0, 0);
        c1 = __builtin_amdgcn_mfma_f32_16x16x32_f16(A1, Bh, c1, 0, 0, 0);
        const int n  = 16 * (4*w + tt) + a;
        const int TN = (WM >= 2) ? (pfx8(n) ^ TL) : 0;
        #pragma unroll
        for (int j = 0; j < 4; ++j) {
            const int m = mb + j;
            int addr;
            if (WM == 0)      addr = (m | (n & 0xF0)) * CSTR + (n & 15);
            else if (WM == 1) addr = ((n & 15) | (m << 4)) * CSTR + (n >> 4);
            else {
                const int tz = TN ^ CTJ[j];
                const int jp = tz ^ ((tz & 1) << 11);
                addr = (WM == 2) ? ((jp >> 4) * CSTR + (jp & 15))
                                 : ((jp & 255) * CSTR + (jp >> 8));
            }
            st[addr] = pkrtz(c0[j], c1[j]);
        }
    }
}

__global__ void __launch_bounds__(BLK) pqm_kernel(
    const float* __restrict__ x,   const float* __restrict__ W1,
    const float* __restrict__ b1,  const float* __restrict__ ln_g,
    const float* __restrict__ ln_b,const float* __restrict__ W2,
    const float* __restrict__ b2,  const float* __restrict__ qw0,
    const float* __restrict__ qw1, const float* __restrict__ qw2,
    const float* __restrict__ scales, const float* __restrict__ biases,
    float* __restrict__ out)
{
    __shared__ unsigned st[256 * CSTR];
    __shared__ float GM[3][NQ][8];
    __shared__ float hb[HD];
    __shared__ float ang[2 * NQ];
    __shared__ float wpar[4][24];

    const int t   = threadIdx.x;
    const int w   = t >> 6;
    const int l   = t & 63;
    const int row = blockIdx.x;

    // ---- P1: stage x row ----
    float* xs = (float*)st;
    if (t < 192) ((float4*)xs)[t] = ((const float4*)(x + row * IND))[t];
    __syncthreads();

    // ---- P2: h = x@W1^T + b1 (24 outs x 8 lanes, threads 0-191); Rot mats ----
    {
        int g = t >> 3, l8 = t & 7;
        if (g < HD) {
            const float* wp = W1 + g * IND + l8 * 96;
            const float* xp = xs + l8 * 96;
            float acc = 0.f;
            #pragma unroll
            for (int j = 0; j < 24; ++j) {
                float4 w4 = *(const float4*)(wp + 4 * j);
                float4 a4 = *(const float4*)(xp + 4 * j);
                acc += a4.x * w4.x + a4.y * w4.y + a4.z * w4.z + a4.w * w4.w;
            }
            acc += __shfl_down(acc, 4, 8);
            acc += __shfl_down(acc, 2, 8);
            acc += __shfl_down(acc, 1, 8);
            if (l8 == 0) hb[g] = acc + b1[g];
        } else if (t >= 192 && t < 228) {
            int u = t - 192; int li = u / NQ, q = u % NQ;
            const float* qw = (li == 0) ? qw0 : ((li == 1) ? qw1 : qw2);
            float phi = qw[q*3+0], th = qw[q*3+1], om = qw[q*3+2];
            float c = cosf(0.5f*th), s = sinf(0.5f*th);
            float sp, cp, sm, cm;
            sincosf(0.5f*(phi+om), &sp, &cp);
            sincosf(0.5f*(phi-om), &sm, &cm);
            float* R = GM[li][q];
            R[0] =  cp*c;  R[1] = -sp*c;
            R[2] = -cm*s;  R[3] = -sm*s;
            R[4] =  cm*s;  R[5] = -sm*s;
            R[6] =  cp*c;  R[7] =  sp*c;
        }
    }
    __syncthreads();

    // ---- P3: LN + ReLU + W2 + tanh -> angles ----
    if (t < NQ) {
        float mu = 0.f;
        #pragma unroll
        for (int j = 0; j < HD; ++j) mu += hb[j];
        mu *= (1.f / HD);
        float var = 0.f;
        #pragma unroll
        for (int j = 0; j < HD; ++j) { float d = hb[j] - mu; var += d * d; }
        var *= (1.f / HD);
        float rinv = 1.f / sqrtf(var + 1e-5f);
        float acc = b2[t];
        #pragma unroll
        for (int j = 0; j < HD; ++j) {
            float hn = (hb[j] - mu) * rinv * ln_g[j] + ln_b[j];
            acc += fmaxf(hn, 0.f) * W2[t * HD + j];
        }
        float a = tanhf(acc);
        ang[t]      = cosf(0.5f * a);
        ang[NQ + t] = sinf(0.5f * a);
    }
    __syncthreads();
    // ---- P4: fuse M = Rot * RY ----
    if (t < 36) {
        int li = t / NQ, q = t % NQ;
        float* R = GM[li][q];
        float r0=R[0],r1=R[1],r2=R[2],r3=R[3],r4=R[4],r5=R[5],r6=R[6],r7=R[7];
        float cr = ang[q], sr = ang[NQ + q];
        R[0] =  r0*cr + r2*sr;  R[1] =  r1*cr + r3*sr;
        R[2] = -r0*sr + r2*cr;  R[3] = -r1*sr + r3*cr;
        R[4] =  r4*cr + r6*sr;  R[5] =  r5*cr + r7*sr;
        R[6] = -r4*sr + r6*cr;  R[7] = -r5*sr + r7*cr;
    }
    __syncthreads();

    // ---- Layer 0 on |0..0>: tensor product, 16 amps/thread; ring fold -> G0 ----
    // j = (t<<4)|r : t bit u = j bit 4+u (qubit 7-u); r bit k = j bit k (qubit 11-k)
    {
        f32x2 v0[16];
        f32x2 lf; lf.x = 1.f; lf.y = 0.f;
        #pragma unroll
        for (int u = 0; u < 8; ++u) {
            const float* F = GM[0][7 - u];
            const int bit = (t >> u) & 1;
            f32x2 e; e.x = F[bit * 4]; e.y = F[bit * 4 + 1];
            lf = pk_cmul(e, lf);
        }
        {
            const float* F = GM[0][11];
            f32x2 e0; e0.x = F[0]; e0.y = F[1];
            f32x2 e1; e1.x = F[4]; e1.y = F[5];
            v0[0] = pk_cmul(e0, lf); v0[1] = pk_cmul(e1, lf);
        }
        #pragma unroll
        for (int b = 1; b < 4; ++b) {
            const float* F = GM[0][11 - b];
            f32x2 e0; e0.x = F[0]; e0.y = F[1];
            f32x2 e1; e1.x = F[4]; e1.y = F[5];
            #pragma unroll
            for (int r = 0; r < (1 << b); ++r) {
                v0[r | (1 << b)] = pk_cmul(e1, v0[r]);
                v0[r]            = pk_cmul(e0, v0[r]);
            }
        }
        const int TL = pfx12(t << 4);
        #pragma unroll
        for (int r = 0; r < 16; ++r) {
            const int tr = r ^ (r >> 1) ^ (r >> 2) ^ (r >> 3);
            const int tz = TL ^ tr;
            const int jp = tz ^ ((tz & 1) << 11);
            st[(jp >> 4) * CSTR + (jp & 15)] = pkrtz(v0[r].x, v0[r].y);
        }
    }

    // ---- Layers 1 & 2: 6 group-GEMM stages ----
    gstage<1, 0, 0>(st, GM, l, w);
    gstage<1, 1, 1>(st, GM, l, w);
    gstage<1, 2, 2>(st, GM, l, w);
    gstage<2, 0, 0>(st, GM, l, w);
    gstage<2, 1, 1>(st, GM, l, w);
    gstage<2, 2, 3>(st, GM, l, w);
    __syncthreads();

    // ---- Measurement: j = (r<<8)|t ; r bits = qubits 3..0, t bits = qubits 11..4 ----
    {
        f32x2 v[16];
        #pragma unroll
        for (int i = 0; i < 4; ++i) {
            uint4 raw = *(const uint4*)(st + t * CSTR + 4 * i);
            v[4*i+0] = unpack2(raw.x); v[4*i+1] = unpack2(raw.y);
            v[4*i+2] = unpack2(raw.z); v[4*i+3] = unpack2(raw.w);
        }
        // eX q0..3: X on r bit (3-q); sum over all r double-counts = required x2
        float ex[5];
        #pragma unroll
        for (int q = 0; q < 4; ++q) {
            f32x2 acc; acc.x = 0.f; acc.y = 0.f;
            const int m = 8 >> q;
            #pragma unroll
            for (int r = 0; r < 16; ++r) pk_fma_plain(acc, v[r], v[r ^ m]);
            ex[q] = acc.x + acc.y;
        }
        // eX q4: j bit 7 -> partner thread t^0x80; thread double-count = x2
        {
            f32x2 acc; acc.x = 0.f; acc.y = 0.f;
            #pragma unroll
            for (int i = 0; i < 4; ++i) {
                uint4 raw = *(const uint4*)(st + (t ^ 0x80) * CSTR + 4 * i);
                f32x2 p0 = unpack2(raw.x), p1 = unpack2(raw.y);
                f32x2 p2 = unpack2(raw.z), p3 = unpack2(raw.w);
                pk_fma_plain(acc, v[4*i+0], p0); pk_fma_plain(acc, v[4*i+1], p1);
                pk_fma_plain(acc, v[4*i+2], p2); pk_fma_plain(acc, v[4*i+3], p3);
            }
            ex[4] = acc.x + acc.y;
        }

        float pr[16];
        #pragma unroll
        for (int r = 0; r < 16; ++r) pr[r] = v[r].x * v[r].x + v[r].y * v[r].y;
        #pragma unroll
        for (int lev = 0; lev < 4; ++lev) {
            const int m = 1 << lev;
            #pragma unroll
            for (int r = 0; r < 16; ++r)
                if (!(r & m)) { float A = pr[r], B = pr[r | m]; pr[r] = A + B; pr[r | m] = A - B; }
        }

        // lane-WHT of pr[0] over 6 lane bits (j bits 0-5 = qubits 11..6)
        float ch = pr[0];
        #pragma unroll
        for (int lev = 0; lev < 6; ++lev) {
            float o = __shfl_xor(ch, 1 << lev, 64);
            ch = (l & (1 << lev)) ? (o - ch) : (ch + o);
        }
        auto wsum = [&](float s) {
            #pragma unroll
            for (int d = 1; d < 64; d <<= 1) s += __shfl_xor(s, d, 64);
            return s;
        };
        float W8 = wsum(pr[8]),  W4 = wsum(pr[4]), W2 = wsum(pr[2]), W1 = wsum(pr[1]);
        float WC = wsum(pr[12]), W6 = wsum(pr[6]), W3 = wsum(pr[3]);
        float e0 = wsum(ex[0]), e1 = wsum(ex[1]), e2 = wsum(ex[2]);
        float e3 = wsum(ex[3]), e4 = wsum(ex[4]);

        if      (l == 0) {
            wpar[w][0]  = ch;
            wpar[w][12] = W8; wpar[w][13] = W4; wpar[w][14] = W2; wpar[w][15] = W1;
            wpar[w][16] = WC; wpar[w][17] = W6; wpar[w][18] = W3;
            wpar[w][19] = e0; wpar[w][20] = e1; wpar[w][21] = e2;
            wpar[w][22] = e3; wpar[w][23] = e4;
        }
        else if (l == 32) wpar[w][1]  = ch;
        else if (l == 16) wpar[w][2]  = ch;
        else if (l == 8)  wpar[w][3]  = ch;
        else if (l == 4)  wpar[w][4]  = ch;
        else if (l == 2)  wpar[w][5]  = ch;
        else if (l == 1)  wpar[w][6]  = ch;
        else if (l == 48) wpar[w][7]  = ch;
        else if (l == 24) wpar[w][8]  = ch;
        else if (l == 12) wpar[w][9]  = ch;
        else if (l == 6)  wpar[w][10] = ch;
        else if (l == 3)  wpar[w][11] = ch;
    }
    __syncthreads();

    if (t < NOBS) {
        // observable -> (per-wave slot, wave-sign mask over w bits)
        const int oslot[NOBS] = {12,13,14,15, 0,0,1,2,3,4,5,6,
                                 16,17,18,15,0,1,7,8,9,10,11,
                                 19,20,21,22,23};
        const int omw[NOBS]   = {0,0,0,0, 2,1,0,0,0,0,0,0,
                                 0,0,0,2,3,1,0,0,0,0,0,
                                 0,0,0,0,0};
        const int sl = oslot[t], mw = omw[t];
        float s = 0.f;
        #pragma unroll
        for (int g = 0; g < 4; ++g) {
            float p = wpar[g][sl];
            s += (__popc(g & mw) & 1) ? -p : p;
        }
        out[row * NOBS + t] = s * scales[t] + biases[t];
    }
}

extern "C" void kernel_launch(void* const* d_in, const int* in_sizes, int n_in,
                              void* d_out, int out_size, void* d_ws, size_t ws_size,
                              hipStream_t stream) {
    const int Bn = in_sizes[0] / IND;   // 1024
    pqm_kernel<<<dim3(Bn), dim3(BLK), 0, stream>>>(
        (const float*)d_in[0], (const float*)d_in[1], (const float*)d_in[2],
        (const float*)d_in[3], (const float*)d_in[4], (const float*)d_in[5],
        (const float*)d_in[6], (const float*)d_in[7], (const float*)d_in[8],
        (const float*)d_in[9], (const float*)d_in[10], (const float*)d_in[11],
        (float*)d_out);
}

// Round 12
// 27.897 us; speedup vs baseline: 1.5992x; 1.0416x over previous
//
#include <hip/hip_runtime.h>
#include <math.h>

#define NQ   12
#define BLK  512
#define IND  768
#define HD   24
#define NOBS 28
#define CSTR 22   // LDS row stride in dwords (88B, 8B-aligned, <=2-way banks)

typedef float    f32x2 __attribute__((ext_vector_type(2)));
typedef float    f32x4 __attribute__((ext_vector_type(4)));
typedef __fp16   f16x2 __attribute__((ext_vector_type(2)));
typedef _Float16 h8    __attribute__((ext_vector_type(8)));

__device__ __forceinline__ unsigned pkrtz(float x, float y) {
    f16x2 h = __builtin_amdgcn_cvt_pkrtz(x, y);
    unsigned u; __builtin_memcpy(&u, &h, 4); return u;
}
__device__ __forceinline__ f32x2 unpack2(unsigned u) {
    f16x2 h; __builtin_memcpy(&h, &u, 4);
    f32x2 v; v.x = (float)h.x; v.y = (float)h.y; return v;
}
__device__ __forceinline__ f32x2 pk_cmul(f32x2 m, f32x2 u) {
    f32x2 r;
    asm("v_pk_mul_f32 %0, %1, %2 op_sel:[0,0] op_sel_hi:[0,1]"
        : "=v"(r) : "v"(m), "v"(u));
    asm("v_pk_fma_f32 %0, %1, %2, %0 op_sel:[1,1,0] op_sel_hi:[1,0,1] neg_lo:[0,1,0]"
        : "+v"(r) : "v"(m), "v"(u));
    return r;
}
__device__ __forceinline__ void pk_fma_plain(f32x2& acc, f32x2 a, f32x2 b) {
    asm("v_pk_fma_f32 %0, %1, %2, %0" : "+v"(acc) : "v"(a), "v"(b));
}
__device__ __forceinline__ h8 as_h8(uint4 u) { h8 r; __builtin_memcpy(&r, &u, 16); return r; }

__device__ __forceinline__ int pfx12(int y) { y ^= y >> 1; y ^= y >> 2; y ^= y >> 4; y ^= y >> 8; return y; }
__device__ __forceinline__ int pfx8 (int y) { y ^= y >> 1; y ^= y >> 2; y ^= y >> 4; return y; }

// 4-qubit group GEMM stage, split over 8 waves (2 N-tiles each).
// WM: 0: G0->G1  1: G1->G2  2: G2->G0 +ring  3: G2->meas +ring
template<int LI, int G, int WM>
__device__ __forceinline__ void gstage(unsigned* st, const float GM[3][NQ][8],
                                       int l, int w) {
    const int a  = l & 15;
    const int mb = (l >> 4) * 4;

    unsigned A0u[4], A1u[4];
    #pragma unroll
    for (int bi = 0; bi < 4; ++bi) {
        const int bq = mb + bi;
        f32x2 u;
        {
            const float* F = GM[LI][11 - 4*G];
            const int off = (a & 1) * 4 + (bq & 1) * 2;
            u.x = F[off]; u.y = F[off + 1];
        }
        #pragma unroll
        for (int p = 1; p < 4; ++p) {
            const float* F = GM[LI][11 - 4*G - p];
            const int off = ((a >> p) & 1) * 4 + ((bq >> p) & 1) * 2;
            f32x2 e; e.x = F[off]; e.y = F[off + 1];
            u = pk_cmul(e, u);
        }
        A0u[bi] = pkrtz(u.x, -u.y);
        A1u[bi] = pkrtz(u.y,  u.x);
    }
    uint4 A04; A04.x = A0u[0]; A04.y = A0u[1]; A04.z = A0u[2]; A04.w = A0u[3];
    uint4 A14; A14.x = A1u[0]; A14.y = A1u[1]; A14.z = A1u[2]; A14.w = A1u[3];
    const h8 A0 = as_h8(A04), A1 = as_h8(A14);

    __syncthreads();                 // prior stage writes visible
    uint2 B0[2], B1[2];
    #pragma unroll
    for (int tt = 0; tt < 2; ++tt) {
        const int base = (16 * (2*w + tt) + a) * CSTR + mb;
        B0[tt] = *(const uint2*)(st + base);
        B1[tt] = *(const uint2*)(st + base + 2);
    }
    __syncthreads();                 // all reads done before any write

    int TL = 0;
    if (WM >= 2) TL = pfx12(mb << 8);
    const int CTJ[4] = {0, 0x1FF, 0x3FF, 0x200};

    #pragma unroll
    for (int tt = 0; tt < 2; ++tt) {
        uint4 b4; b4.x = B0[tt].x; b4.y = B0[tt].y; b4.z = B1[tt].x; b4.w = B1[tt].y;
        f32x4 c0 = {0.f, 0.f, 0.f, 0.f}, c1 = {0.f, 0.f, 0.f, 0.f};
        const h8 Bh = as_h8(b4);
        c0 = __builtin_amdgcn_mfma_f32_16x16x32_f16(A0, Bh, c0, 0, 0, 0);
        c1 = __builtin_amdgcn_mfma_f32_16x16x32_f16(A1, Bh, c1, 0, 0, 0);
        const int n  = 16 * (2*w + tt) + a;
        const int TN = (WM >= 2) ? (pfx8(n) ^ TL) : 0;
        #pragma unroll
        for (int j = 0; j < 4; ++j) {
            const int m = mb + j;
            int addr;
            if (WM == 0)      addr = (m | (n & 0xF0)) * CSTR + (n & 15);
            else if (WM == 1) addr = ((n & 15) | (m << 4)) * CSTR + (n >> 4);
            else {
                const int tz = TN ^ CTJ[j];
                const int jp = tz ^ ((tz & 1) << 11);
                addr = (WM == 2) ? ((jp >> 4) * CSTR + (jp & 15))
                                 : ((jp & 255) * CSTR + (jp >> 8));
            }
            st[addr] = pkrtz(c0[j], c1[j]);
        }
    }
}

__global__ void __launch_bounds__(BLK, 4) pqm_kernel(
    const float* __restrict__ x,   const float* __restrict__ W1,
    const float* __restrict__ b1,  const float* __restrict__ ln_g,
    const float* __restrict__ ln_b,const float* __restrict__ W2,
    const float* __restrict__ b2,  const float* __restrict__ qw0,
    const float* __restrict__ qw1, const float* __restrict__ qw2,
    const float* __restrict__ scales, const float* __restrict__ biases,
    float* __restrict__ out)
{
    __shared__ unsigned st[256 * CSTR];
    __shared__ float GM[3][NQ][8];
    __shared__ float hb[HD];
    __shared__ float ang[2 * NQ];
    __shared__ float wpar[8][22];

    const int t   = threadIdx.x;
    const int w   = t >> 6;          // wave 0..7
    const int l   = t & 63;          // lane
    const int row = blockIdx.x;

    // ---- P1: stage x row ----
    float* xs = (float*)st;
    if (t < 192) ((float4*)xs)[t] = ((const float4*)(x + row * IND))[t];
    __syncthreads();

    // ---- P2: h = x@W1^T + b1 (24 outs x 16 lanes, 12 float4/lane); Rot mats ----
    {
        int g = t >> 4, l16 = t & 15;
        if (g < HD) {
            const float* wp = W1 + g * IND;
            float acc = 0.f;
            #pragma unroll
            for (int k = 0; k < 12; ++k) {
                const int f4 = l16 + 16 * k;        // float4 index 0..191
                float4 a4 = ((const float4*)xs)[f4];
                float4 w4 = *(const float4*)(wp + 4 * f4);
                acc += a4.x * w4.x + a4.y * w4.y + a4.z * w4.z + a4.w * w4.w;
            }
            acc += __shfl_down(acc, 8, 16);
            acc += __shfl_down(acc, 4, 16);
            acc += __shfl_down(acc, 2, 16);
            acc += __shfl_down(acc, 1, 16);
            if (l16 == 0) hb[g] = acc + b1[g];
        } else if (t >= 448 && t < 484) {
            int u = t - 448; int li = u / NQ, q = u % NQ;
            const float* qw = (li == 0) ? qw0 : ((li == 1) ? qw1 : qw2);
            float phi = qw[q*3+0], th = qw[q*3+1], om = qw[q*3+2];
            float c = cosf(0.5f*th), s = sinf(0.5f*th);
            float sp, cp, sm, cm;
            sincosf(0.5f*(phi+om), &sp, &cp);
            sincosf(0.5f*(phi-om), &sm, &cm);
            float* R = GM[li][q];
            R[0] =  cp*c;  R[1] = -sp*c;
            R[2] = -cm*s;  R[3] = -sm*s;
            R[4] =  cm*s;  R[5] = -sm*s;
            R[6] =  cp*c;  R[7] =  sp*c;
        }
    }
    __syncthreads();

    // ---- P3: LN + ReLU + W2 + tanh -> angles ----
    if (t < NQ) {
        float mu = 0.f;
        #pragma unroll
        for (int j = 0; j < HD; ++j) mu += hb[j];
        mu *= (1.f / HD);
        float var = 0.f;
        #pragma unroll
        for (int j = 0; j < HD; ++j) { float d = hb[j] - mu; var += d * d; }
        var *= (1.f / HD);
        float rinv = 1.f / sqrtf(var + 1e-5f);
        float acc = b2[t];
        #pragma unroll
        for (int j = 0; j < HD; ++j) {
            float hn = (hb[j] - mu) * rinv * ln_g[j] + ln_b[j];
            acc += fmaxf(hn, 0.f) * W2[t * HD + j];
        }
        float a = tanhf(acc);
        ang[t]      = cosf(0.5f * a);
        ang[NQ + t] = sinf(0.5f * a);
    }
    __syncthreads();
    // ---- P4: fuse M = Rot * RY ----
    if (t < 36) {
        int li = t / NQ, q = t % NQ;
        float* R = GM[li][q];
        float r0=R[0],r1=R[1],r2=R[2],r3=R[3],r4=R[4],r5=R[5],r6=R[6],r7=R[7];
        float cr = ang[q], sr = ang[NQ + q];
        R[0] =  r0*cr + r2*sr;  R[1] =  r1*cr + r3*sr;
        R[2] = -r0*sr + r2*cr;  R[3] = -r1*sr + r3*cr;
        R[4] =  r4*cr + r6*sr;  R[5] =  r5*cr + r7*sr;
        R[6] = -r4*sr + r6*cr;  R[7] = -r5*sr + r7*cr;
    }
    __syncthreads();

    // ---- Layer 0 on |0..0>: tensor product, 8 amps/thread; ring fold -> G0 ----
    // j = (t<<3)|r : t bit u = j bit 3+u (qubit 8-u); r bit k = j bit k (qubit 11-k)
    {
        f32x2 v0[8];
        f32x2 lf; lf.x = 1.f; lf.y = 0.f;
        #pragma unroll
        for (int u = 0; u < 9; ++u) {
            const float* F = GM[0][8 - u];
            const int bit = (t >> u) & 1;
            f32x2 e; e.x = F[bit * 4]; e.y = F[bit * 4 + 1];
            lf = pk_cmul(e, lf);
        }
        {
            const float* F = GM[0][11];
            f32x2 e0; e0.x = F[0]; e0.y = F[1];
            f32x2 e1; e1.x = F[4]; e1.y = F[5];
            v0[0] = pk_cmul(e0, lf); v0[1] = pk_cmul(e1, lf);
        }
        #pragma unroll
        for (int b = 1; b < 3; ++b) {
            const float* F = GM[0][11 - b];
            f32x2 e0; e0.x = F[0]; e0.y = F[1];
            f32x2 e1; e1.x = F[4]; e1.y = F[5];
            #pragma unroll
            for (int r = 0; r < (1 << b); ++r) {
                v0[r | (1 << b)] = pk_cmul(e1, v0[r]);
                v0[r]            = pk_cmul(e0, v0[r]);
            }
        }
        const int TL = pfx12(t << 3);
        #pragma unroll
        for (int r = 0; r < 8; ++r) {
            const int tr = r ^ (r >> 1) ^ (r >> 2);
            const int tz = TL ^ tr;
            const int jp = tz ^ ((tz & 1) << 11);
            st[(jp >> 4) * CSTR + (jp & 15)] = pkrtz(v0[r].x, v0[r].y);
        }
    }

    // ---- Layers 1 & 2: 6 group-GEMM stages ----
    gstage<1, 0, 0>(st, GM, l, w);
    gstage<1, 1, 1>(st, GM, l, w);
    gstage<1, 2, 2>(st, GM, l, w);
    gstage<2, 0, 0>(st, GM, l, w);
    gstage<2, 1, 1>(st, GM, l, w);
    gstage<2, 2, 3>(st, GM, l, w);
    __syncthreads();

    // ---- Measurement: amp j at row j&255, dword j>>8 (true final state) ----
    // thread: R = t&255 (j bits 7..0 = qubits 4..11), h = t>>8 (j bit 11 = qubit 0),
    //         reg r = j bits 10..8 (qubits 1,2,3)
    {
        const int R = t & 255, h = t >> 8;
        const int rowb = R * CSTR + 8 * h;
        f32x2 v[8];
        #pragma unroll
        for (int p = 0; p < 4; ++p) {
            uint2 raw = *(const uint2*)(st + rowb + 2 * p);
            v[2*p]   = unpack2(raw.x);
            v[2*p+1] = unpack2(raw.y);
        }
        float ex[5];
        // q1..q3: register-pair sums (double count over r = required x2)
        #pragma unroll
        for (int q = 1; q <= 3; ++q) {
            f32x2 acc; acc.x = 0.f; acc.y = 0.f;
            const int m = 8 >> q;
            #pragma unroll
            for (int r = 0; r < 8; ++r) pk_fma_plain(acc, v[r], v[r ^ m]);
            ex[q] = acc.x + acc.y;
        }
        // q0: partner = other dword half (j bit 11); thread double-count = x2
        {
            f32x2 acc; acc.x = 0.f; acc.y = 0.f;
            const int pb = R * CSTR + 8 * (h ^ 1);
            #pragma unroll
            for (int p = 0; p < 4; ++p) {
                uint2 raw = *(const uint2*)(st + pb + 2 * p);
                pk_fma_plain(acc, v[2*p],   unpack2(raw.x));
                pk_fma_plain(acc, v[2*p+1], unpack2(raw.y));
            }
            ex[0] = acc.x + acc.y;
        }
        // q4: partner row R^128 (j bit 7); thread double-count = x2
        {
            f32x2 acc; acc.x = 0.f; acc.y = 0.f;
            const int pb = (R ^ 128) * CSTR + 8 * h;
            #pragma unroll
            for (int p = 0; p < 4; ++p) {
                uint2 raw = *(const uint2*)(st + pb + 2 * p);
                pk_fma_plain(acc, v[2*p],   unpack2(raw.x));
                pk_fma_plain(acc, v[2*p+1], unpack2(raw.y));
            }
            ex[4] = acc.x + acc.y;
        }

        // probabilities + 3-level register WHT over r (q1,q2,q3)
        #pragma unroll
        for (int r = 0; r < 8; ++r) v[r].x = v[r].x * v[r].x + v[r].y * v[r].y;
        #pragma unroll
        for (int lev = 0; lev < 3; ++lev) {
            const int m = 1 << lev;
            #pragma unroll
            for (int r = 0; r < 8; ++r)
                if (!(r & m)) { float A = v[r].x, B = v[r | m].x; v[r].x = A + B; v[r | m].x = A - B; }
        }

        // lane WHT of W[0] over 6 lane bits (qubits 6..11)
        float ch = v[0].x;
        #pragma unroll
        for (int lev = 0; lev < 6; ++lev) {
            float o = __shfl_xor(ch, 1 << lev, 64);
            ch = (l & (1 << lev)) ? (o - ch) : (ch + o);
        }
        auto wsum = [&](float s) {
            #pragma unroll
            for (int d = 1; d < 64; d <<= 1) s += __shfl_xor(s, d, 64);
            return s;
        };
        float W4 = wsum(v[4].x), W2 = wsum(v[2].x), W1s = wsum(v[1].x);
        float W6 = wsum(v[6].x), W3 = wsum(v[3].x);
        float e0 = wsum(ex[0]), e1 = wsum(ex[1]), e2 = wsum(ex[2]);
        float e3 = wsum(ex[3]), e4 = wsum(ex[4]);

        if      (l == 0) {
            wpar[w][0]  = ch;
            wpar[w][12] = W4;  wpar[w][13] = W2; wpar[w][14] = W1s;
            wpar[w][15] = W6;  wpar[w][16] = W3;
            wpar[w][17] = e0;  wpar[w][18] = e1; wpar[w][19] = e2;
            wpar[w][20] = e3;  wpar[w][21] = e4;
        }
        else if (l == 32) wpar[w][1]  = ch;
        else if (l == 16) wpar[w][2]  = ch;
        else if (l == 8)  wpar[w][3]  = ch;
        else if (l == 4)  wpar[w][4]  = ch;
        else if (l == 2)  wpar[w][5]  = ch;
        else if (l == 1)  wpar[w][6]  = ch;
        else if (l == 48) wpar[w][7]  = ch;
        else if (l == 24) wpar[w][8]  = ch;
        else if (l == 12) wpar[w][9]  = ch;
        else if (l == 6)  wpar[w][10] = ch;
        else if (l == 3)  wpar[w][11] = ch;
    }
    __syncthreads();

    if (t < NOBS) {
        // observable -> (per-wave slot, wave-sign mask: w bit0=q5, bit1=q4, bit2=q0)
        const int oslot[NOBS] = {0,12,13,14, 0,0, 1,2,3,4,5,6,
                                 12,15,16,14, 0,1, 7,8,9,10,11,
                                 17,18,19,20,21};
        const int omw[NOBS]   = {4,0,0,0, 2,1, 0,0,0,0,0,0,
                                 4,0,0,2, 3,1, 0,0,0,0,0,
                                 0,0,0,0,0};
        const int sl = oslot[t], mw = omw[t];
        float s = 0.f;
        #pragma unroll
        for (int g = 0; g < 8; ++g) {
            float p = wpar[g][sl];
            s += (__popc(g & mw) & 1) ? -p : p;
        }
        out[row * NOBS + t] = s * scales[t] + biases[t];
    }
}

extern "C" void kernel_launch(void* const* d_in, const int* in_sizes, int n_in,
                              void* d_out, int out_size, void* d_ws, size_t ws_size,
                              hipStream_t stream) {
    const int Bn = in_sizes[0] / IND;   // 1024
    pqm_kernel<<<dim3(Bn), dim3(BLK), 0, stream>>>(
        (const float*)d_in[0], (const float*)d_in[1], (const float*)d_in[2],
        (const float*)d_in[3], (const float*)d_in[4], (const float*)d_in[5],
        (const float*)d_in[6], (const float*)d_in[7], (const float*)d_in[8],
        (const float*)d_in[9], (const float*)d_in[10], (const float*)d_in[11],
        (float*)d_out);
}

// Round 13
// 26.557 us; speedup vs baseline: 1.6799x; 1.0505x over previous
//
#include <hip/hip_runtime.h>
#include <math.h>

#define NQ   12
#define BLK  512
#define IND  768
#define HD   24
#define NOBS 28
#define CSTR 20   // LDS row stride in dwords (80B, 16B-aligned)

typedef float    f32x2 __attribute__((ext_vector_type(2)));
typedef float    f32x4 __attribute__((ext_vector_type(4)));
typedef __fp16   f16x2 __attribute__((ext_vector_type(2)));
typedef _Float16 h8    __attribute__((ext_vector_type(8)));

__device__ __forceinline__ unsigned pkrtz(float x, float y) {
    f16x2 h = __builtin_amdgcn_cvt_pkrtz(x, y);
    unsigned u; __builtin_memcpy(&u, &h, 4); return u;
}
__device__ __forceinline__ f32x2 unpack2(unsigned u) {
    f16x2 h; __builtin_memcpy(&h, &u, 4);
    f32x2 v; v.x = (float)h.x; v.y = (float)h.y; return v;
}
__device__ __forceinline__ f32x2 pk_cmul(f32x2 m, f32x2 u) {
    f32x2 r;
    asm("v_pk_mul_f32 %0, %1, %2 op_sel:[0,0] op_sel_hi:[0,1]"
        : "=v"(r) : "v"(m), "v"(u));
    asm("v_pk_fma_f32 %0, %1, %2, %0 op_sel:[1,1,0] op_sel_hi:[1,0,1] neg_lo:[0,1,0]"
        : "+v"(r) : "v"(m), "v"(u));
    return r;
}
__device__ __forceinline__ void pk_fma_plain(f32x2& acc, f32x2 a, f32x2 b) {
    asm("v_pk_fma_f32 %0, %1, %2, %0" : "+v"(acc) : "v"(a), "v"(b));
}
__device__ __forceinline__ h8 as_h8(uint4 u) { h8 r; __builtin_memcpy(&r, &u, 16); return r; }

__device__ __forceinline__ int pfx12(int y) { y ^= y >> 1; y ^= y >> 2; y ^= y >> 4; y ^= y >> 8; return y; }
__device__ __forceinline__ int pfx8 (int y) { y ^= y >> 1; y ^= y >> 2; y ^= y >> 4; return y; }

// 4-qubit group GEMM stage, 8 waves x 2 N-tiles; A-fragments preloaded from LDS.
// S = stage index 0..5 ; WM: 0: G0->G1  1: G1->G2  2: G2->G0 +ring  3: G2->meas +ring
template<int S, int WM>
__device__ __forceinline__ void gstage(unsigned* st, const unsigned* Afr,
                                       int l, int w) {
    const int a  = l & 15;
    const int mb = (l >> 4) * 4;

    __syncthreads();                 // prior stage writes visible
    const unsigned* Ap = Afr + (S * 64 + l) * 8;
    const uint4 A04 = *(const uint4*)(Ap);
    const uint4 A14 = *(const uint4*)(Ap + 4);
    uint4 Bf[2];
    #pragma unroll
    for (int tt = 0; tt < 2; ++tt)
        Bf[tt] = *(const uint4*)(st + (16 * (2*w + tt) + a) * CSTR + mb);
    __syncthreads();                 // all reads done before any write

    const h8 A0 = as_h8(A04), A1 = as_h8(A14);
    int TL = 0;
    if (WM >= 2) TL = pfx12(mb << 8);
    const int CTJ[4] = {0, 0x1FF, 0x3FF, 0x200};

    #pragma unroll
    for (int tt = 0; tt < 2; ++tt) {
        f32x4 c0 = {0.f, 0.f, 0.f, 0.f}, c1 = {0.f, 0.f, 0.f, 0.f};
        const h8 Bh = as_h8(Bf[tt]);
        c0 = __builtin_amdgcn_mfma_f32_16x16x32_f16(A0, Bh, c0, 0, 0, 0);
        c1 = __builtin_amdgcn_mfma_f32_16x16x32_f16(A1, Bh, c1, 0, 0, 0);
        const int n = 16 * (2*w + tt) + a;
        if (WM == 0) {
            const int base = (mb + (n & 0xF0)) * CSTR + (n & 15);
            #pragma unroll
            for (int j = 0; j < 4; ++j)
                st[base + j * CSTR] = pkrtz(c0[j], c1[j]);
        } else if (WM == 1) {
            const int base = ((n & 15) + mb * 16) * CSTR + (n >> 4);
            #pragma unroll
            for (int j = 0; j < 4; ++j)
                st[base + j * 16 * CSTR] = pkrtz(c0[j], c1[j]);
        } else {
            const int TN = pfx8(n) ^ TL;
            #pragma unroll
            for (int j = 0; j < 4; ++j) {
                const int tz = TN ^ CTJ[j];
                const int jp = tz ^ ((tz & 1) << 11);
                const int addr = (WM == 2) ? ((jp >> 4) * CSTR + (jp & 15))
                                           : ((jp & 255) * CSTR + (jp >> 8));
                st[addr] = pkrtz(c0[j], c1[j]);
            }
        }
    }
}

__global__ void __launch_bounds__(BLK, 4) pqm_kernel(
    const float* __restrict__ x,   const float* __restrict__ W1,
    const float* __restrict__ b1,  const float* __restrict__ ln_g,
    const float* __restrict__ ln_b,const float* __restrict__ W2,
    const float* __restrict__ b2,  const float* __restrict__ qw0,
    const float* __restrict__ qw1, const float* __restrict__ qw2,
    const float* __restrict__ scales, const float* __restrict__ biases,
    float* __restrict__ out)
{
    __shared__ unsigned st[256 * CSTR];    // 20 KB state
    __shared__ unsigned Afr[6 * 64 * 8];   // 12 KB precomputed A-fragments
    __shared__ float GM[3][NQ][8];
    __shared__ float hb[HD];
    __shared__ float ang[2 * NQ];
    __shared__ float wpar[8][22];

    const int t   = threadIdx.x;
    const int w   = t >> 6;          // wave 0..7
    const int l   = t & 63;          // lane
    const int row = blockIdx.x;

    // ---- P1: stage x row ----
    float* xs = (float*)st;
    if (t < 192) ((float4*)xs)[t] = ((const float4*)(x + row * IND))[t];
    __syncthreads();

    // ---- P2: h = x@W1^T + b1 (24 outs x 16 lanes, 12 float4/lane); Rot mats ----
    {
        int g = t >> 4, l16 = t & 15;
        if (g < HD) {
            const float* wp = W1 + g * IND;
            float acc = 0.f;
            #pragma unroll
            for (int k = 0; k < 12; ++k) {
                const int f4 = l16 + 16 * k;        // float4 index 0..191
                float4 a4 = ((const float4*)xs)[f4];
                float4 w4 = *(const float4*)(wp + 4 * f4);
                acc += a4.x * w4.x + a4.y * w4.y + a4.z * w4.z + a4.w * w4.w;
            }
            acc += __shfl_down(acc, 8, 16);
            acc += __shfl_down(acc, 4, 16);
            acc += __shfl_down(acc, 2, 16);
            acc += __shfl_down(acc, 1, 16);
            if (l16 == 0) hb[g] = acc + b1[g];
        } else if (t >= 448 && t < 484) {
            int u = t - 448; int li = u / NQ, q = u % NQ;
            const float* qw = (li == 0) ? qw0 : ((li == 1) ? qw1 : qw2);
            float phi = qw[q*3+0], th = qw[q*3+1], om = qw[q*3+2];
            float c = cosf(0.5f*th), s = sinf(0.5f*th);
            float sp, cp, sm, cm;
            sincosf(0.5f*(phi+om), &sp, &cp);
            sincosf(0.5f*(phi-om), &sm, &cm);
            float* R = GM[li][q];
            R[0] =  cp*c;  R[1] = -sp*c;
            R[2] = -cm*s;  R[3] = -sm*s;
            R[4] =  cm*s;  R[5] = -sm*s;
            R[6] =  cp*c;  R[7] =  sp*c;
        }
    }
    __syncthreads();

    // ---- P3: LN + ReLU + W2 + tanh -> angles ----
    if (t < NQ) {
        float mu = 0.f;
        #pragma unroll
        for (int j = 0; j < HD; ++j) mu += hb[j];
        mu *= (1.f / HD);
        float var = 0.f;
        #pragma unroll
        for (int j = 0; j < HD; ++j) { float d = hb[j] - mu; var += d * d; }
        var *= (1.f / HD);
        float rinv = 1.f / sqrtf(var + 1e-5f);
        float acc = b2[t];
        #pragma unroll
        for (int j = 0; j < HD; ++j) {
            float hn = (hb[j] - mu) * rinv * ln_g[j] + ln_b[j];
            acc += fmaxf(hn, 0.f) * W2[t * HD + j];
        }
        float a = tanhf(acc);
        ang[t]      = cosf(0.5f * a);
        ang[NQ + t] = sinf(0.5f * a);
    }
    __syncthreads();
    // ---- P4: fuse M = Rot * RY ----
    if (t < 36) {
        int li = t / NQ, q = t % NQ;
        float* R = GM[li][q];
        float r0=R[0],r1=R[1],r2=R[2],r3=R[3],r4=R[4],r5=R[5],r6=R[6],r7=R[7];
        float cr = ang[q], sr = ang[NQ + q];
        R[0] =  r0*cr + r2*sr;  R[1] =  r1*cr + r3*sr;
        R[2] = -r0*sr + r2*cr;  R[3] = -r1*sr + r3*cr;
        R[4] =  r4*cr + r6*sr;  R[5] =  r5*cr + r7*sr;
        R[6] = -r4*sr + r6*cr;  R[7] = -r5*sr + r7*cr;
    }
    __syncthreads();

    // ---- A-fragment precompute: thread (s,lane) builds stage s, lane's frags ----
    if (t < 384) {
        const int s = t >> 6, lane = t & 63;
        const int LI = 1 + s / 3, G = s % 3;
        const int a = lane & 15, mb = (lane >> 4) * 4;
        unsigned* Ap = Afr + (s * 64 + lane) * 8;
        #pragma unroll
        for (int bi = 0; bi < 4; ++bi) {
            const int bq = mb + bi;
            f32x2 u;
            {
                const float* F = GM[LI][11 - 4*G];
                const int off = (a & 1) * 4 + (bq & 1) * 2;
                u.x = F[off]; u.y = F[off + 1];
            }
            #pragma unroll
            for (int p = 1; p < 4; ++p) {
                const float* F = GM[LI][11 - 4*G - p];
                const int off = ((a >> p) & 1) * 4 + ((bq >> p) & 1) * 2;
                f32x2 e; e.x = F[off]; e.y = F[off + 1];
                u = pk_cmul(e, u);
            }
            Ap[bi]     = pkrtz(u.x, -u.y);   // Cr row
            Ap[4 + bi] = pkrtz(u.y,  u.x);   // Ci row
        }
    }

    // ---- Layer 0 on |0..0>: tensor product, 8 amps/thread; ring fold -> G0 ----
    // j = (t<<3)|r : t bit u = j bit 3+u (qubit 8-u); r bit k = j bit k (qubit 11-k)
    {
        f32x2 v0[8];
        f32x2 lf; lf.x = 1.f; lf.y = 0.f;
        #pragma unroll
        for (int u = 0; u < 9; ++u) {
            const float* F = GM[0][8 - u];
            const int bit = (t >> u) & 1;
            f32x2 e; e.x = F[bit * 4]; e.y = F[bit * 4 + 1];
            lf = pk_cmul(e, lf);
        }
        {
            const float* F = GM[0][11];
            f32x2 e0; e0.x = F[0]; e0.y = F[1];
            f32x2 e1; e1.x = F[4]; e1.y = F[5];
            v0[0] = pk_cmul(e0, lf); v0[1] = pk_cmul(e1, lf);
        }
        #pragma unroll
        for (int b = 1; b < 3; ++b) {
            const float* F = GM[0][11 - b];
            f32x2 e0; e0.x = F[0]; e0.y = F[1];
            f32x2 e1; e1.x = F[4]; e1.y = F[5];
            #pragma unroll
            for (int r = 0; r < (1 << b); ++r) {
                v0[r | (1 << b)] = pk_cmul(e1, v0[r]);
                v0[r]            = pk_cmul(e0, v0[r]);
            }
        }
        const int TL = pfx12(t << 3);
        #pragma unroll
        for (int r = 0; r < 8; ++r) {
            const int tr = r ^ (r >> 1) ^ (r >> 2);
            const int tz = TL ^ tr;
            const int jp = tz ^ ((tz & 1) << 11);
            st[(jp >> 4) * CSTR + (jp & 15)] = pkrtz(v0[r].x, v0[r].y);
        }
    }

    // ---- Layers 1 & 2: 6 group-GEMM stages (A from LDS) ----
    gstage<0, 0>(st, Afr, l, w);
    gstage<1, 1>(st, Afr, l, w);
    gstage<2, 2>(st, Afr, l, w);
    gstage<3, 0>(st, Afr, l, w);
    gstage<4, 1>(st, Afr, l, w);
    gstage<5, 3>(st, Afr, l, w);
    __syncthreads();

    // ---- Measurement: amp j at row j&255, dword j>>8 (true final state) ----
    // thread: R = t&255 (j bits 7..0 = qubits 4..11), h = t>>8 (j bit 11 = qubit 0),
    //         reg r = j bits 10..8 (qubits 1,2,3)
    {
        const int R = t & 255, h = t >> 8;
        const int rowb = R * CSTR + 8 * h;
        f32x2 v[8];
        #pragma unroll
        for (int p = 0; p < 4; ++p) {
            uint2 raw = *(const uint2*)(st + rowb + 2 * p);
            v[2*p]   = unpack2(raw.x);
            v[2*p+1] = unpack2(raw.y);
        }
        float ex[5];
        // q1..q3: register-pair sums (double count over r = required x2)
        #pragma unroll
        for (int q = 1; q <= 3; ++q) {
            f32x2 acc; acc.x = 0.f; acc.y = 0.f;
            const int m = 8 >> q;
            #pragma unroll
            for (int r = 0; r < 8; ++r) pk_fma_plain(acc, v[r], v[r ^ m]);
            ex[q] = acc.x + acc.y;
        }
        // q0: partner = other dword half (j bit 11); thread double-count = x2
        {
            f32x2 acc; acc.x = 0.f; acc.y = 0.f;
            const int pb = R * CSTR + 8 * (h ^ 1);
            #pragma unroll
            for (int p = 0; p < 4; ++p) {
                uint2 raw = *(const uint2*)(st + pb + 2 * p);
                pk_fma_plain(acc, v[2*p],   unpack2(raw.x));
                pk_fma_plain(acc, v[2*p+1], unpack2(raw.y));
            }
            ex[0] = acc.x + acc.y;
        }
        // q4: partner row R^128 (j bit 7); thread double-count = x2
        {
            f32x2 acc; acc.x = 0.f; acc.y = 0.f;
            const int pb = (R ^ 128) * CSTR + 8 * h;
            #pragma unroll
            for (int p = 0; p < 4; ++p) {
                uint2 raw = *(const uint2*)(st + pb + 2 * p);
                pk_fma_plain(acc, v[2*p],   unpack2(raw.x));
                pk_fma_plain(acc, v[2*p+1], unpack2(raw.y));
            }
            ex[4] = acc.x + acc.y;
        }

        // probabilities + 3-level register WHT over r (q1,q2,q3)
        #pragma unroll
        for (int r = 0; r < 8; ++r) v[r].x = v[r].x * v[r].x + v[r].y * v[r].y;
        #pragma unroll
        for (int lev = 0; lev < 3; ++lev) {
            const int m = 1 << lev;
            #pragma unroll
            for (int r = 0; r < 8; ++r)
                if (!(r & m)) { float A = v[r].x, B = v[r | m].x; v[r].x = A + B; v[r | m].x = A - B; }
        }

        // lane WHT of W[0] over 6 lane bits (qubits 6..11)
        float ch = v[0].x;
        #pragma unroll
        for (int lev = 0; lev < 6; ++lev) {
            float o = __shfl_xor(ch, 1 << lev, 64);
            ch = (l & (1 << lev)) ? (o - ch) : (ch + o);
        }
        auto wsum = [&](float s) {
            #pragma unroll
            for (int d = 1; d < 64; d <<= 1) s += __shfl_xor(s, d, 64);
            return s;
        };
        float W4 = wsum(v[4].x), W2 = wsum(v[2].x), W1s = wsum(v[1].x);
        float W6 = wsum(v[6].x), W3 = wsum(v[3].x);
        float e0 = wsum(ex[0]), e1 = wsum(ex[1]), e2 = wsum(ex[2]);
        float e3 = wsum(ex[3]), e4 = wsum(ex[4]);

        if      (l == 0) {
            wpar[w][0]  = ch;
            wpar[w][12] = W4;  wpar[w][13] = W2; wpar[w][14] = W1s;
            wpar[w][15] = W6;  wpar[w][16] = W3;
            wpar[w][17] = e0;  wpar[w][18] = e1; wpar[w][19] = e2;
            wpar[w][20] = e3;  wpar[w][21] = e4;
        }
        else if (l == 32) wpar[w][1]  = ch;
        else if (l == 16) wpar[w][2]  = ch;
        else if (l == 8)  wpar[w][3]  = ch;
        else if (l == 4)  wpar[w][4]  = ch;
        else if (l == 2)  wpar[w][5]  = ch;
        else if (l == 1)  wpar[w][6]  = ch;
        else if (l == 48) wpar[w][7]  = ch;
        else if (l == 24) wpar[w][8]  = ch;
        else if (l == 12) wpar[w][9]  = ch;
        else if (l == 6)  wpar[w][10] = ch;
        else if (l == 3)  wpar[w][11] = ch;
    }
    __syncthreads();

    if (t < NOBS) {
        // observable -> (per-wave slot, wave-sign mask: w bit0=q5, bit1=q4, bit2=q0)
        const int oslot[NOBS] = {0,12,13,14, 0,0, 1,2,3,4,5,6,
                                 12,15,16,14, 0,1, 7,8,9,10,11,
                                 17,18,19,20,21};
        const int omw[NOBS]   = {4,0,0,0, 2,1, 0,0,0,0,0,0,
                                 4,0,0,2, 3,1, 0,0,0,0,0,
                                 0,0,0,0,0};
        const int sl = oslot[t], mw = omw[t];
        float s = 0.f;
        #pragma unroll
        for (int g = 0; g < 8; ++g) {
            float p = wpar[g][sl];
            s += (__popc(g & mw) & 1) ? -p : p;
        }
        out[row * NOBS + t] = s * scales[t] + biases[t];
    }
}

extern "C" void kernel_launch(void* const* d_in, const int* in_sizes, int n_in,
                              void* d_out, int out_size, void* d_ws, size_t ws_size,
                              hipStream_t stream) {
    const int Bn = in_sizes[0] / IND;   // 1024
    pqm_kernel<<<dim3(Bn), dim3(BLK), 0, stream>>>(
        (const float*)d_in[0], (const float*)d_in[1], (const float*)d_in[2],
        (const float*)d_in[3], (const float*)d_in[4], (const float*)d_in[5],
        (const float*)d_in[6], (const float*)d_in[7], (const float*)d_in[8],
        (const float*)d_in[9], (const float*)d_in[10], (const float*)d_in[11],
        (float*)d_out);
}